// Round 1
// baseline (366.202 us; speedup 1.0000x reference)
//
#include <hip/hip_runtime.h>
#include <hip/hip_bf16.h>
#include <math.h>

// Problem constants (fixed by setup_inputs)
#define B_SZ 2
#define N_SEQ 2048
#define DIM 512
#define H_HEADS 8
#define D_HEAD 64
#define K_NN 32
#define M_DB 131072

// ---------------------------------------------------------------------------
// Mask-layout detection: mem_mask is numpy bool. Harness may ship it as
// 1-byte bools or widened int32. If int32 (values 0/1), every byte at offset
// 1,2,3 (mod 4) is zero. Scan first 4KB; any nonzero there => byte layout.
// ---------------------------------------------------------------------------
__global__ void detect_mask_layout(const unsigned char* __restrict__ mb,
                                   int* __restrict__ flag) {
    int t = threadIdx.x;  // 64 threads
    unsigned char v = 0;
    for (int e = t; e < 1024; e += 64) {
        v |= mb[4 * e + 1];
        v |= mb[4 * e + 2];
        v |= mb[4 * e + 3];
    }
    unsigned long long any = __ballot(v != 0);
    if (t == 0) *flag = (any != 0ull) ? 1 : 0;  // 1 = byte layout, 0 = int32
}

// ---------------------------------------------------------------------------
// NT GEMM: C[m,j] = sum_k A[m,k] * W[j,k]
// A: (Mdim, Kdim) row-major; W: (Ndim, Kdim) row-major; C: (Mdim, Ndim)
// 64x64 block tile, BK=32, 256 threads, 4x4 per-thread micro-tile.
// A/W tiles stored transposed in LDS ([k][m]) so fragment reads are b128.
// ---------------------------------------------------------------------------
#define BM 64
#define BN 64
#define BK 32

__global__ __launch_bounds__(256) void gemm_nt(const float* __restrict__ A,
                                               const float* __restrict__ W,
                                               float* __restrict__ C,
                                               int Mdim, int Ndim, int Kdim) {
    __shared__ float As[BK][BM];  // 8 KB
    __shared__ float Ws[BK][BN];  // 8 KB
    const int bm = blockIdx.x;
    const int bn = blockIdx.y;
    const int t = threadIdx.x;
    const int tx = t & 15;   // N direction
    const int ty = t >> 4;   // M direction
    float acc[4][4] = {};

    const float* Ablk = A + (size_t)(bm * BM) * Kdim;
    const float* Wblk = W + (size_t)(bn * BN) * Kdim;

    for (int k0 = 0; k0 < Kdim; k0 += BK) {
        // Stage tiles: 64 rows x 32 k = 512 float4s per tile, 2 per thread.
#pragma unroll
        for (int r = 0; r < 2; ++r) {
            int idx = t + r * 256;        // 0..511
            int m = idx >> 3;             // 0..63
            int kk = (idx & 7) << 2;      // 0,4,...,28
            float4 va = *(const float4*)(Ablk + (size_t)m * Kdim + k0 + kk);
            As[kk + 0][m] = va.x; As[kk + 1][m] = va.y;
            As[kk + 2][m] = va.z; As[kk + 3][m] = va.w;
            float4 vw = *(const float4*)(Wblk + (size_t)m * Kdim + k0 + kk);
            Ws[kk + 0][m] = vw.x; Ws[kk + 1][m] = vw.y;
            Ws[kk + 2][m] = vw.z; Ws[kk + 3][m] = vw.w;
        }
        __syncthreads();
#pragma unroll
        for (int kk = 0; kk < BK; ++kk) {
            float4 a = *(const float4*)&As[kk][ty << 2];
            float4 b = *(const float4*)&Ws[kk][tx << 2];
            float av[4] = {a.x, a.y, a.z, a.w};
            float bv[4] = {b.x, b.y, b.z, b.w};
#pragma unroll
            for (int i = 0; i < 4; ++i)
#pragma unroll
                for (int j = 0; j < 4; ++j)
                    acc[i][j] = fmaf(av[i], bv[j], acc[i][j]);
        }
        __syncthreads();
    }
#pragma unroll
    for (int i = 0; i < 4; ++i) {
        int m = bm * BM + (ty << 2) + i;
        float4 o = {acc[i][0], acc[i][1], acc[i][2], acc[i][3]};
        *(float4*)(C + (size_t)m * Ndim + bn * BN + (tx << 2)) = o;
    }
}

// ---------------------------------------------------------------------------
// Attention: one wave per (b, h, i) query. lane = d (0..63).
// q-normalize (with 1e-12 clip), gather K=32 k/v rows (contiguous 512B each),
// butterfly-reduce dot, online softmax (m=-inf init, masked = -FLT_MAX
// reproduces jax uniform-softmax for all-masked rows).
// ---------------------------------------------------------------------------
__global__ __launch_bounds__(256) void attn_kernel(
    const float* __restrict__ qbuf,       // [b*n][512]
    const float* __restrict__ mem_db,     // [b][M][128]
    const int* __restrict__ knn_idx,      // [b][h][n][K]
    const void* __restrict__ mem_mask,    // [b][h][n][K] bool-or-int32
    const float* __restrict__ scale_param,// [h]
    const int* __restrict__ flag,
    float* __restrict__ outbuf)           // [b*n][512]
{
    const int wave = blockIdx.x * (blockDim.x >> 6) + (threadIdx.x >> 6);
    const int lane = threadIdx.x & 63;
    // wave -> (bi, hi, i); i fastest so idx/mask reads are contiguous
    const int i = wave % N_SEQ;
    const int bh = wave / N_SEQ;
    const int hi = bh % H_HEADS;
    const int bi = bh / H_HEADS;

    const int bytelayout = *flag;  // uniform

    const float* qrow = qbuf + (size_t)(bi * N_SEQ + i) * DIM + hi * D_HEAD;
    float qv = qrow[lane];
    float ss = qv * qv;
#pragma unroll
    for (int s = 32; s; s >>= 1) ss += __shfl_xor(ss, s);
    float nrm = sqrtf(ss);
    qv = qv / fmaxf(nrm, 1e-12f);

    const float scale = __expf(scale_param[hi]);

    const size_t kb = ((size_t)(bi * H_HEADS + hi) * N_SEQ + i) * K_NN;
    int idxv = 0, maskv = 0;
    if (lane < K_NN) {
        idxv = knn_idx[kb + lane];
        if (bytelayout)
            maskv = ((const unsigned char*)mem_mask)[kb + lane] ? 1 : 0;
        else
            maskv = ((const int*)mem_mask)[kb + lane] ? 1 : 0;
    }

    const float* dbb = mem_db + (size_t)bi * M_DB * 2 * D_HEAD;
    float m_run = -INFINITY, l_run = 0.f, o_run = 0.f;
#pragma unroll 1
    for (int j = 0; j < K_NN; ++j) {
        int idx = __shfl(idxv, j);
        int msk = __shfl(maskv, j);
        const float* row = dbb + (size_t)idx * (2 * D_HEAD);
        float kk = row[lane];
        float vv = row[D_HEAD + lane];
        float p = qv * kk;
#pragma unroll
        for (int s = 32; s; s >>= 1) p += __shfl_xor(p, s);
        float sim = msk ? p * scale : -3.402823466e38f;
        float m_new = fmaxf(m_run, sim);
        float alpha = __expf(m_run - m_new);
        float w = __expf(sim - m_new);
        l_run = l_run * alpha + w;
        o_run = o_run * alpha + w * vv;
        m_run = m_new;
    }
    outbuf[(size_t)(bi * N_SEQ + i) * DIM + hi * D_HEAD + lane] = o_run / l_run;
}

// ---------------------------------------------------------------------------
extern "C" void kernel_launch(void* const* d_in, const int* in_sizes, int n_in,
                              void* d_out, int out_size, void* d_ws, size_t ws_size,
                              hipStream_t stream) {
    const float* x          = (const float*)d_in[0];
    const float* mem_db     = (const float*)d_in[1];
    const int*   knn_idx    = (const int*)d_in[2];
    const void*  mem_mask   = d_in[3];
    const float* Wq         = (const float*)d_in[4];
    // d_in[5] = Wkv: dead code in reference, unused.
    const float* Wout       = (const float*)d_in[6];
    const float* scale_p    = (const float*)d_in[7];
    float* out = (float*)d_out;

    const int Mrows = B_SZ * N_SEQ;  // 4096

    int*   flag     = (int*)d_ws;
    float* qbuf     = (float*)((char*)d_ws + 256);
    float* attn_out = qbuf + (size_t)Mrows * DIM;

    detect_mask_layout<<<1, 64, 0, stream>>>((const unsigned char*)mem_mask, flag);

    dim3 ggrid(Mrows / BM, DIM / BN);  // (64, 8)
    gemm_nt<<<ggrid, 256, 0, stream>>>(x, Wq, qbuf, Mrows, DIM, DIM);

    const int n_waves = B_SZ * H_HEADS * N_SEQ;  // 32768
    attn_kernel<<<n_waves / 4, 256, 0, stream>>>(qbuf, mem_db, knn_idx, mem_mask,
                                                 scale_p, flag, attn_out);

    gemm_nt<<<ggrid, 256, 0, stream>>>(attn_out, Wout, out, Mrows, DIM, DIM);
}

// Round 2
// 352.117 us; speedup vs baseline: 1.0400x; 1.0400x over previous
//
#include <hip/hip_runtime.h>
#include <hip/hip_bf16.h>
#include <math.h>

// Problem constants (fixed by setup_inputs)
#define B_SZ 2
#define N_SEQ 2048
#define DIM 512
#define H_HEADS 8
#define D_HEAD 64
#define K_NN 32
#define M_DB 131072

typedef __attribute__((ext_vector_type(8))) short bf16x8;
typedef __attribute__((ext_vector_type(4))) float f32x4;

// ---------------------------------------------------------------------------
// Mask-layout detection (numpy bool may arrive as 1-byte or widened int32).
// ---------------------------------------------------------------------------
__global__ void detect_mask_layout(const unsigned char* __restrict__ mb,
                                   int* __restrict__ flag) {
    int t = threadIdx.x;  // 64 threads
    unsigned char v = 0;
    for (int e = t; e < 1024; e += 64) {
        v |= mb[4 * e + 1];
        v |= mb[4 * e + 2];
        v |= mb[4 * e + 3];
    }
    unsigned long long any = __ballot(v != 0);
    if (t == 0) *flag = (any != 0ull) ? 1 : 0;  // 1 = byte layout, 0 = int32
}

// ---------------------------------------------------------------------------
// fp32 -> split bf16 (hi + lo planes). a ~= hi + lo to ~2^-17 relative.
// ---------------------------------------------------------------------------
__device__ __forceinline__ unsigned short f2bf_rn(float x) {
    unsigned int u = __float_as_uint(x);
    u += 0x7fffu + ((u >> 16) & 1u);
    return (unsigned short)(u >> 16);
}

__global__ __launch_bounds__(256) void split_bf16(const float4* __restrict__ src,
                                                  ushort4* __restrict__ hi,
                                                  ushort4* __restrict__ lo,
                                                  int n4) {
    int i = blockIdx.x * 256 + threadIdx.x;
    if (i >= n4) return;
    float4 a = src[i];
    ushort4 h, l;
    h.x = f2bf_rn(a.x); l.x = f2bf_rn(a.x - __uint_as_float((unsigned)h.x << 16));
    h.y = f2bf_rn(a.y); l.y = f2bf_rn(a.y - __uint_as_float((unsigned)h.y << 16));
    h.z = f2bf_rn(a.z); l.z = f2bf_rn(a.z - __uint_as_float((unsigned)h.z << 16));
    h.w = f2bf_rn(a.w); l.w = f2bf_rn(a.w - __uint_as_float((unsigned)h.w << 16));
    hi[i] = h; lo[i] = l;
}

// ---------------------------------------------------------------------------
// Split-bf16 MFMA GEMM (NT): C[m,n] = sum_k A[m,k] * W[n,k], fp32-accurate via
// 3 passes (ah*bh + ah*bl + al*bh). No LDS: fragments loaded straight from
// global (each load = 16 fully-consumed 64B lines; L1/L2 serve re-reads).
// Block: 256 thr = 4 waves, 64x64 tile; wave = 32x32 = 2x2 of 16x16x32 mfma.
// A-frag layout: m = lane&15, k = (lane>>4)*8 + j. C/D: col=lane&15,
// row=(lane>>4)*4+reg  [HW-verified mappings].
// ---------------------------------------------------------------------------
__global__ __launch_bounds__(256) void gemm_mfma_split(
    const unsigned short* __restrict__ Ahi, const unsigned short* __restrict__ Alo,
    const unsigned short* __restrict__ Bhi, const unsigned short* __restrict__ Blo,
    float* __restrict__ C, int Mdim, int Ndim, int Kdim)
{
    const int t = threadIdx.x;
    const int wave = t >> 6, lane = t & 63;
    const int r = lane & 15, qd = lane >> 4;
    const int m0 = blockIdx.x * 64 + (wave & 1) * 32;
    const int n0 = blockIdx.y * 64 + (wave >> 1) * 32;

    f32x4 acc[2][2];
#pragma unroll
    for (int i = 0; i < 2; ++i)
#pragma unroll
        for (int j = 0; j < 2; ++j) acc[i][j] = (f32x4){0.f, 0.f, 0.f, 0.f};

    const size_t a0 = (size_t)(m0 + r) * Kdim + qd * 8;
    const size_t a1 = a0 + (size_t)16 * Kdim;
    const size_t b0 = (size_t)(n0 + r) * Kdim + qd * 8;
    const size_t b1 = b0 + (size_t)16 * Kdim;

    for (int k0 = 0; k0 < Kdim; k0 += 32) {
        bf16x8 ah0 = *(const bf16x8*)(Ahi + a0 + k0);
        bf16x8 ah1 = *(const bf16x8*)(Ahi + a1 + k0);
        bf16x8 al0 = *(const bf16x8*)(Alo + a0 + k0);
        bf16x8 al1 = *(const bf16x8*)(Alo + a1 + k0);
        bf16x8 bh0 = *(const bf16x8*)(Bhi + b0 + k0);
        bf16x8 bh1 = *(const bf16x8*)(Bhi + b1 + k0);
        bf16x8 bl0 = *(const bf16x8*)(Blo + b0 + k0);
        bf16x8 bl1 = *(const bf16x8*)(Blo + b1 + k0);

        acc[0][0] = __builtin_amdgcn_mfma_f32_16x16x32_bf16(ah0, bh0, acc[0][0], 0, 0, 0);
        acc[0][1] = __builtin_amdgcn_mfma_f32_16x16x32_bf16(ah0, bh1, acc[0][1], 0, 0, 0);
        acc[1][0] = __builtin_amdgcn_mfma_f32_16x16x32_bf16(ah1, bh0, acc[1][0], 0, 0, 0);
        acc[1][1] = __builtin_amdgcn_mfma_f32_16x16x32_bf16(ah1, bh1, acc[1][1], 0, 0, 0);

        acc[0][0] = __builtin_amdgcn_mfma_f32_16x16x32_bf16(ah0, bl0, acc[0][0], 0, 0, 0);
        acc[0][1] = __builtin_amdgcn_mfma_f32_16x16x32_bf16(ah0, bl1, acc[0][1], 0, 0, 0);
        acc[1][0] = __builtin_amdgcn_mfma_f32_16x16x32_bf16(ah1, bl0, acc[1][0], 0, 0, 0);
        acc[1][1] = __builtin_amdgcn_mfma_f32_16x16x32_bf16(ah1, bl1, acc[1][1], 0, 0, 0);

        acc[0][0] = __builtin_amdgcn_mfma_f32_16x16x32_bf16(al0, bh0, acc[0][0], 0, 0, 0);
        acc[0][1] = __builtin_amdgcn_mfma_f32_16x16x32_bf16(al0, bh1, acc[0][1], 0, 0, 0);
        acc[1][0] = __builtin_amdgcn_mfma_f32_16x16x32_bf16(al1, bh0, acc[1][0], 0, 0, 0);
        acc[1][1] = __builtin_amdgcn_mfma_f32_16x16x32_bf16(al1, bh1, acc[1][1], 0, 0, 0);
    }

#pragma unroll
    for (int mt = 0; mt < 2; ++mt)
#pragma unroll
        for (int nt = 0; nt < 2; ++nt)
#pragma unroll
            for (int rr = 0; rr < 4; ++rr)
                C[(size_t)(m0 + mt * 16 + qd * 4 + rr) * Ndim + n0 + nt * 16 + r] =
                    acc[mt][nt][rr];
}

// ---------------------------------------------------------------------------
// Attention: one wave per (b,h,i) query, lane = d. Two-phase for MLP:
// issue all 64 gather loads (32 k + 32 v rows, 256B coalesced each) into
// registers first, then reduce. Softmax: lane j holds sim_j (lanes>=32 hold
// -inf); masked = -FLT_MAX reproduces jax uniform softmax for all-masked rows.
// ---------------------------------------------------------------------------
__global__ __launch_bounds__(256) void attn_kernel(
    const float* __restrict__ qbuf,       // [b*n][512]
    const float* __restrict__ mem_db,     // [b][M][128]
    const int* __restrict__ knn_idx,      // [b][h][n][K]
    const void* __restrict__ mem_mask,    // [b][h][n][K] bool-or-int32
    const float* __restrict__ scale_param,// [h]
    const int* __restrict__ flag,
    float* __restrict__ outbuf)           // [b*n][512]
{
    const int wave = blockIdx.x * (blockDim.x >> 6) + (threadIdx.x >> 6);
    const int lane = threadIdx.x & 63;
    const int i = wave % N_SEQ;
    const int bh = wave / N_SEQ;
    const int hi = bh % H_HEADS;
    const int bi = bh / H_HEADS;

    const int bytelayout = *flag;  // uniform

    const float* qrow = qbuf + (size_t)(bi * N_SEQ + i) * DIM + hi * D_HEAD;
    float qv = qrow[lane];
    float ss = qv * qv;
#pragma unroll
    for (int s = 32; s; s >>= 1) ss += __shfl_xor(ss, s);
    qv = qv / fmaxf(sqrtf(ss), 1e-12f);

    const float scale = __expf(scale_param[hi]);

    const size_t kb = ((size_t)(bi * H_HEADS + hi) * N_SEQ + i) * K_NN;
    int idxv = 0, maskv = 0;
    if (lane < K_NN) {
        idxv = knn_idx[kb + lane];
        if (bytelayout)
            maskv = ((const unsigned char*)mem_mask)[kb + lane] ? 1 : 0;
        else
            maskv = ((const int*)mem_mask)[kb + lane] ? 1 : 0;
    }

    const float* dbb = mem_db + (size_t)bi * M_DB * 2 * D_HEAD;

    // Phase 1: gather everything (64 independent 256B loads in flight)
    float kreg[K_NN], vreg[K_NN];
#pragma unroll
    for (int j = 0; j < K_NN; ++j) {
        int idx = __shfl(idxv, j);
        const float* row = dbb + (size_t)idx * (2 * D_HEAD);
        kreg[j] = row[lane];
        vreg[j] = row[D_HEAD + lane];
    }

    // Phase 2: 32 dot products; lane j keeps sim_j
    float simlane = -INFINITY;
#pragma unroll
    for (int j = 0; j < K_NN; ++j) {
        float p = qv * kreg[j];
#pragma unroll
        for (int s = 32; s; s >>= 1) p += __shfl_xor(p, s);
        int msk = __shfl(maskv, j);
        float sim = msk ? p * scale : -3.402823466e38f;
        if (lane == j) simlane = sim;
    }

    // Phase 3: softmax across lanes
    float m = simlane;
#pragma unroll
    for (int s = 32; s; s >>= 1) m = fmaxf(m, __shfl_xor(m, s));
    float w = __expf(simlane - m);  // lanes>=32: exp(-inf - finite) = 0
    float l = w;
#pragma unroll
    for (int s = 32; s; s >>= 1) l += __shfl_xor(l, s);
    float winv = w / l;

    // Phase 4: weighted sum of v rows
    float o = 0.f;
#pragma unroll
    for (int j = 0; j < K_NN; ++j)
        o = fmaf(__shfl(winv, j), vreg[j], o);

    outbuf[(size_t)(bi * N_SEQ + i) * DIM + hi * D_HEAD + lane] = o;
}

// ---------------------------------------------------------------------------
extern "C" void kernel_launch(void* const* d_in, const int* in_sizes, int n_in,
                              void* d_out, int out_size, void* d_ws, size_t ws_size,
                              hipStream_t stream) {
    const float* x        = (const float*)d_in[0];
    const float* mem_db   = (const float*)d_in[1];
    const int*   knn_idx  = (const int*)d_in[2];
    const void*  mem_mask = d_in[3];
    const float* Wq       = (const float*)d_in[4];
    // d_in[5] = Wkv: dead code in the reference, unused.
    const float* Wout     = (const float*)d_in[6];
    const float* scale_p  = (const float*)d_in[7];
    float* out = (float*)d_out;

    const int Mrows   = B_SZ * N_SEQ;          // 4096
    const int n_x     = Mrows * DIM;           // 2097152
    const int n_w     = DIM * DIM;             // 262144

    // Workspace layout (peak ~17.5 MB):
    //  [0,256)                      : mask-layout flag
    //  W region (1 MB)              : Wq planes, then Wout planes
    //  region A (8 MB)              : x hi/lo planes, then attn_out (fp32)
    //  region B (8 MB)              : qbuf (fp32), then attn_out hi/lo planes
    char* ws = (char*)d_ws;
    int* flag = (int*)ws;
    unsigned short* w_hi = (unsigned short*)(ws + 256);
    unsigned short* w_lo = w_hi + n_w;
    char* regA = ws + 256 + (size_t)2 * n_w * sizeof(unsigned short);
    char* regB = regA + (size_t)n_x * sizeof(float);
    unsigned short* x_hi = (unsigned short*)regA;
    unsigned short* x_lo = x_hi + n_x;
    float* attn_out = (float*)regA;
    float* qbuf = (float*)regB;
    unsigned short* ao_hi = (unsigned short*)regB;
    unsigned short* ao_lo = ao_hi + n_x;

    detect_mask_layout<<<1, 64, 0, stream>>>((const unsigned char*)mem_mask, flag);

    // Split x and Wq into bf16 hi/lo planes
    split_bf16<<<n_x / 1024, 256, 0, stream>>>((const float4*)x, (ushort4*)x_hi,
                                               (ushort4*)x_lo, n_x / 4);
    split_bf16<<<n_w / 1024, 256, 0, stream>>>((const float4*)Wq, (ushort4*)w_hi,
                                               (ushort4*)w_lo, n_w / 4);

    dim3 ggrid(Mrows / 64, DIM / 64);  // (64, 8)
    gemm_mfma_split<<<ggrid, 256, 0, stream>>>(x_hi, x_lo, w_hi, w_lo, qbuf,
                                               Mrows, DIM, DIM);

    const int n_waves = B_SZ * H_HEADS * N_SEQ;  // 32768
    attn_kernel<<<n_waves / 4, 256, 0, stream>>>(qbuf, mem_db, knn_idx, mem_mask,
                                                 scale_p, flag, attn_out);

    // Split attn_out and Wout, then output projection
    split_bf16<<<n_x / 1024, 256, 0, stream>>>((const float4*)attn_out,
                                               (ushort4*)ao_hi, (ushort4*)ao_lo,
                                               n_x / 4);
    split_bf16<<<n_w / 1024, 256, 0, stream>>>((const float4*)Wout, (ushort4*)w_hi,
                                               (ushort4*)w_lo, n_w / 4);
    gemm_mfma_split<<<ggrid, 256, 0, stream>>>(ao_hi, ao_lo, w_hi, w_lo, out,
                                               Mrows, DIM, DIM);
}

// Round 3
// 309.291 us; speedup vs baseline: 1.1840x; 1.1385x over previous
//
#include <hip/hip_runtime.h>
#include <hip/hip_bf16.h>
#include <math.h>

// Problem constants (fixed by setup_inputs)
#define B_SZ 2
#define N_SEQ 2048
#define DIM 512
#define H_HEADS 8
#define D_HEAD 64
#define K_NN 32
#define M_DB 131072

typedef __attribute__((ext_vector_type(8))) short bf16x8;
typedef __attribute__((ext_vector_type(4))) float f32x4;

// ---------------------------------------------------------------------------
// Mask-layout detection (numpy bool may arrive as 1-byte or widened int32).
// ---------------------------------------------------------------------------
__global__ void detect_mask_layout(const unsigned char* __restrict__ mb,
                                   int* __restrict__ flag) {
    int t = threadIdx.x;  // 64 threads
    unsigned char v = 0;
    for (int e = t; e < 1024; e += 64) {
        v |= mb[4 * e + 1];
        v |= mb[4 * e + 2];
        v |= mb[4 * e + 3];
    }
    unsigned long long any = __ballot(v != 0);
    if (t == 0) *flag = (any != 0ull) ? 1 : 0;  // 1 = byte layout, 0 = int32
}

// ---------------------------------------------------------------------------
// fp32 -> (hi, lo) bf16 split, in-register. f ~= hi + lo to ~2^-17 relative.
// ---------------------------------------------------------------------------
__device__ __forceinline__ void cvt_hi_lo(float f, short& h, short& l) {
    unsigned u = __float_as_uint(f);
    unsigned uh = u + (0x7fffu + ((u >> 16) & 1u));
    h = (short)(uh >> 16);
    float r = f - __uint_as_float((uh >> 16) << 16);
    unsigned ur = __float_as_uint(r);
    l = (short)((ur + (0x7fffu + ((ur >> 16) & 1u))) >> 16);
}

__device__ __forceinline__ void load_frag_split(const float* __restrict__ p,
                                                bf16x8& h, bf16x8& l) {
    float4 f0 = *(const float4*)p;
    float4 f1 = *(const float4*)(p + 4);
    float ff[8] = {f0.x, f0.y, f0.z, f0.w, f1.x, f1.y, f1.z, f1.w};
#pragma unroll
    for (int e = 0; e < 8; ++e) {
        short hh, ll;
        cvt_hi_lo(ff[e], hh, ll);
        h[e] = hh; l[e] = ll;
    }
}

// ---------------------------------------------------------------------------
// fp32-accurate MFMA GEMM (NT): C[m,n] = sum_k A[m,k] * W[n,k].
// fp32 inputs loaded from global, split to bf16 hi/lo in-register, 3 MFMA
// passes (hh + hl + lh) recover ~fp32 accuracy. No LDS.
// Block: 256 thr = 4 waves, 64x64 tile; wave = 32x32 = 2x2 of 16x16x32 mfma.
// A-frag: m=lane&15, k=(lane>>4)*8+j.  C/D: col=lane&15, row=(lane>>4)*4+reg.
// ---------------------------------------------------------------------------
__global__ __launch_bounds__(256) void gemm_mfma_f32(
    const float* __restrict__ A, const float* __restrict__ W,
    float* __restrict__ C, int Mdim, int Ndim, int Kdim)
{
    const int t = threadIdx.x;
    const int wave = t >> 6, lane = t & 63;
    const int r = lane & 15, qd = lane >> 4;
    const int m0 = blockIdx.x * 64 + (wave & 1) * 32;
    const int n0 = blockIdx.y * 64 + (wave >> 1) * 32;

    f32x4 acc[2][2];
#pragma unroll
    for (int i = 0; i < 2; ++i)
#pragma unroll
        for (int j = 0; j < 2; ++j) acc[i][j] = (f32x4){0.f, 0.f, 0.f, 0.f};

    const float* pa0 = A + (size_t)(m0 + r) * Kdim + qd * 8;
    const float* pa1 = pa0 + (size_t)16 * Kdim;
    const float* pb0 = W + (size_t)(n0 + r) * Kdim + qd * 8;
    const float* pb1 = pb0 + (size_t)16 * Kdim;

    for (int k0 = 0; k0 < Kdim; k0 += 32) {
        bf16x8 ah0, al0, ah1, al1, bh0, bl0, bh1, bl1;
        load_frag_split(pa0 + k0, ah0, al0);
        load_frag_split(pa1 + k0, ah1, al1);
        load_frag_split(pb0 + k0, bh0, bl0);
        load_frag_split(pb1 + k0, bh1, bl1);

        acc[0][0] = __builtin_amdgcn_mfma_f32_16x16x32_bf16(ah0, bh0, acc[0][0], 0, 0, 0);
        acc[0][1] = __builtin_amdgcn_mfma_f32_16x16x32_bf16(ah0, bh1, acc[0][1], 0, 0, 0);
        acc[1][0] = __builtin_amdgcn_mfma_f32_16x16x32_bf16(ah1, bh0, acc[1][0], 0, 0, 0);
        acc[1][1] = __builtin_amdgcn_mfma_f32_16x16x32_bf16(ah1, bh1, acc[1][1], 0, 0, 0);

        acc[0][0] = __builtin_amdgcn_mfma_f32_16x16x32_bf16(ah0, bl0, acc[0][0], 0, 0, 0);
        acc[0][1] = __builtin_amdgcn_mfma_f32_16x16x32_bf16(ah0, bl1, acc[0][1], 0, 0, 0);
        acc[1][0] = __builtin_amdgcn_mfma_f32_16x16x32_bf16(ah1, bl0, acc[1][0], 0, 0, 0);
        acc[1][1] = __builtin_amdgcn_mfma_f32_16x16x32_bf16(ah1, bl1, acc[1][1], 0, 0, 0);

        acc[0][0] = __builtin_amdgcn_mfma_f32_16x16x32_bf16(al0, bh0, acc[0][0], 0, 0, 0);
        acc[0][1] = __builtin_amdgcn_mfma_f32_16x16x32_bf16(al0, bh1, acc[0][1], 0, 0, 0);
        acc[1][0] = __builtin_amdgcn_mfma_f32_16x16x32_bf16(al1, bh0, acc[1][0], 0, 0, 0);
        acc[1][1] = __builtin_amdgcn_mfma_f32_16x16x32_bf16(al1, bh1, acc[1][1], 0, 0, 0);
    }

#pragma unroll
    for (int mt = 0; mt < 2; ++mt)
#pragma unroll
        for (int nt = 0; nt < 2; ++nt)
#pragma unroll
            for (int rr = 0; rr < 4; ++rr)
                C[(size_t)(m0 + mt * 16 + qd * 4 + rr) * Ndim + n0 + nt * 16 + r] =
                    acc[mt][nt][rr];
}

// ---------------------------------------------------------------------------
// Attention: one wave per (b,h,i) query. float4 gather: lane l = 16*grp+sub
// loads 16B of row (4g+grp); one wave-load fetches 4 rows (1KB). Dots reduce
// over 16 lanes (4 butterfly steps). Softmax across lanes (lane j holds
// sim_j, lanes>=32 -inf; masked = -FLT_MAX => jax uniform softmax on
// all-masked rows). Output reduced over grp, stored by 16 lanes as float4.
// ---------------------------------------------------------------------------
__global__ __launch_bounds__(256) void attn_kernel(
    const float* __restrict__ qbuf,       // [b*n][512]
    const float* __restrict__ mem_db,     // [b][M][128]
    const int* __restrict__ knn_idx,      // [b][h][n][K]
    const void* __restrict__ mem_mask,    // [b][h][n][K] bool-or-int32
    const float* __restrict__ scale_param,// [h]
    const int* __restrict__ flag,
    float* __restrict__ outbuf)           // [b*n][512]
{
    const int wave = blockIdx.x * 4 + (threadIdx.x >> 6);
    const int lane = threadIdx.x & 63;
    const int sub = lane & 15, grp = lane >> 4;
    const int i = wave % N_SEQ;
    const int bh = wave / N_SEQ;
    const int hi = bh % H_HEADS;
    const int bi = bh / H_HEADS;

    const int bytelayout = *flag;  // uniform

    const float* qrow = qbuf + (size_t)(bi * N_SEQ + i) * DIM + hi * D_HEAD;
    float qv = qrow[lane];
    float ss = qv * qv;
#pragma unroll
    for (int s = 32; s; s >>= 1) ss += __shfl_xor(ss, s);
    qv = qv / fmaxf(sqrtf(ss), 1e-12f);

    // q in float4-per-lane layout: q4[c] = q[4*sub + c]
    float q4[4];
#pragma unroll
    for (int c = 0; c < 4; ++c) q4[c] = __shfl(qv, 4 * sub + c);

    const float scale = __expf(scale_param[hi]);

    const size_t kb = ((size_t)(bi * H_HEADS + hi) * N_SEQ + i) * K_NN;
    int idxv = 0, maskv = 0;
    if (lane < K_NN) {
        idxv = knn_idx[kb + lane];
        if (bytelayout)
            maskv = ((const unsigned char*)mem_mask)[kb + lane] ? 1 : 0;
        else
            maskv = ((const int*)mem_mask)[kb + lane] ? 1 : 0;
    }

    const float* dbb = mem_db + (size_t)bi * M_DB * (2 * D_HEAD);

    // Gather: group g covers rows 4g..4g+3; my row = 4g+grp, my 16B = [4*sub..]
    float4 kk[8], vv[8];
#pragma unroll
    for (int g = 0; g < 8; ++g) {
        int idx = __shfl(idxv, 4 * g + grp);
        const float* row = dbb + (size_t)idx * (2 * D_HEAD);
        kk[g] = *(const float4*)(row + 4 * sub);
        vv[g] = *(const float4*)(row + D_HEAD + 4 * sub);
    }

    // Dot products: 4-elem partial per lane, 4-step butterfly over 16 lanes
    float s8[8];
#pragma unroll
    for (int g = 0; g < 8; ++g) {
        float p = q4[0] * kk[g].x + q4[1] * kk[g].y + q4[2] * kk[g].z + q4[3] * kk[g].w;
        p += __shfl_xor(p, 1);
        p += __shfl_xor(p, 2);
        p += __shfl_xor(p, 4);
        p += __shfl_xor(p, 8);
        s8[g] = p;  // full dot of row 4g+grp (replicated in 16-lane group)
    }

    // Collect: lane j<32 takes s8[j>>2] from source lane (j&3)<<4
    float simlane = -INFINITY;
#pragma unroll
    for (int g = 0; g < 8; ++g) {
        float tv = __shfl(s8[g], (lane & 3) << 4);
        if ((lane >> 2) == g) simlane = tv;  // lanes>=32 never match: stay -inf
    }
    if (lane < K_NN)
        simlane = maskv ? simlane * scale : -3.402823466e38f;

    // Softmax across 64 lanes
    float m = simlane;
#pragma unroll
    for (int s = 32; s; s >>= 1) m = fmaxf(m, __shfl_xor(m, s));
    float w = __expf(simlane - m);
    float l = w;
#pragma unroll
    for (int s = 32; s; s >>= 1) l += __shfl_xor(l, s);
    float winv = w / l;

    // Weighted sum of V (float4 layout), then reduce across the 4 groups
    float4 o = {0.f, 0.f, 0.f, 0.f};
#pragma unroll
    for (int g = 0; g < 8; ++g) {
        float wg = __shfl(winv, 4 * g + grp);
        o.x = fmaf(wg, vv[g].x, o.x);
        o.y = fmaf(wg, vv[g].y, o.y);
        o.z = fmaf(wg, vv[g].z, o.z);
        o.w = fmaf(wg, vv[g].w, o.w);
    }
#pragma unroll
    for (int s = 16; s <= 32; s <<= 1) {
        o.x += __shfl_xor(o.x, s);
        o.y += __shfl_xor(o.y, s);
        o.z += __shfl_xor(o.z, s);
        o.w += __shfl_xor(o.w, s);
    }
    if (grp == 0)
        *(float4*)(outbuf + (size_t)(bi * N_SEQ + i) * DIM + hi * D_HEAD + 4 * sub) = o;
}

// ---------------------------------------------------------------------------
extern "C" void kernel_launch(void* const* d_in, const int* in_sizes, int n_in,
                              void* d_out, int out_size, void* d_ws, size_t ws_size,
                              hipStream_t stream) {
    const float* x        = (const float*)d_in[0];
    const float* mem_db   = (const float*)d_in[1];
    const int*   knn_idx  = (const int*)d_in[2];
    const void*  mem_mask = d_in[3];
    const float* Wq       = (const float*)d_in[4];
    // d_in[5] = Wkv: dead code in the reference, unused.
    const float* Wout     = (const float*)d_in[6];
    const float* scale_p  = (const float*)d_in[7];
    float* out = (float*)d_out;

    const int Mrows = B_SZ * N_SEQ;  // 4096
    const int n_x   = Mrows * DIM;   // 2097152

    // Workspace: flag | qbuf (8MB) | attn_out (8MB)
    char* ws = (char*)d_ws;
    int* flag = (int*)ws;
    float* qbuf     = (float*)(ws + 256);
    float* attn_out = qbuf + (size_t)n_x;

    detect_mask_layout<<<1, 64, 0, stream>>>((const unsigned char*)mem_mask, flag);

    dim3 ggrid(Mrows / 64, DIM / 64);  // (64, 8)
    gemm_mfma_f32<<<ggrid, 256, 0, stream>>>(x, Wq, qbuf, Mrows, DIM, DIM);

    const int n_waves = B_SZ * H_HEADS * N_SEQ;  // 32768
    attn_kernel<<<n_waves / 4, 256, 0, stream>>>(qbuf, mem_db, knn_idx, mem_mask,
                                                 scale_p, flag, attn_out);

    gemm_mfma_f32<<<ggrid, 256, 0, stream>>>(attn_out, Wout, out, Mrows, DIM, DIM);
}

// Round 4
// 289.093 us; speedup vs baseline: 1.2667x; 1.0699x over previous
//
#include <hip/hip_runtime.h>
#include <hip/hip_bf16.h>
#include <math.h>

// Problem constants (fixed by setup_inputs)
#define B_SZ 2
#define N_SEQ 2048
#define DIM 512
#define H_HEADS 8
#define D_HEAD 64
#define K_NN 32
#define M_DB 131072

typedef __attribute__((ext_vector_type(8))) short bf16x8;
typedef __attribute__((ext_vector_type(4))) float f32x4;

// ---------------------------------------------------------------------------
// Mask-layout detection (numpy bool may arrive as 1-byte or widened int32).
// ---------------------------------------------------------------------------
__global__ void detect_mask_layout(const unsigned char* __restrict__ mb,
                                   int* __restrict__ flag) {
    int t = threadIdx.x;  // 64 threads
    unsigned char v = 0;
    for (int e = t; e < 1024; e += 64) {
        v |= mb[4 * e + 1];
        v |= mb[4 * e + 2];
        v |= mb[4 * e + 3];
    }
    unsigned long long any = __ballot(v != 0);
    if (t == 0) *flag = (any != 0ull) ? 1 : 0;  // 1 = byte layout, 0 = int32
}

// ---------------------------------------------------------------------------
// fp32 -> (hi, lo) bf16 split, in-register. f ~= hi + lo to ~2^-17 relative.
// ---------------------------------------------------------------------------
__device__ __forceinline__ void cvt_hi_lo(float f, short& h, short& l) {
    unsigned u = __float_as_uint(f);
    unsigned uh = u + (0x7fffu + ((u >> 16) & 1u));
    h = (short)(uh >> 16);
    float r = f - __uint_as_float((uh >> 16) << 16);
    unsigned ur = __float_as_uint(r);
    l = (short)((ur + (0x7fffu + ((ur >> 16) & 1u))) >> 16);
}

__device__ __forceinline__ void load_frag_split(const float* __restrict__ p,
                                                bf16x8& h, bf16x8& l) {
    float4 f0 = *(const float4*)p;
    float4 f1 = *(const float4*)(p + 4);
    float ff[8] = {f0.x, f0.y, f0.z, f0.w, f1.x, f1.y, f1.z, f1.w};
#pragma unroll
    for (int e = 0; e < 8; ++e) {
        short hh, ll;
        cvt_hi_lo(ff[e], hh, ll);
        h[e] = hh; l[e] = ll;
    }
}

// ---------------------------------------------------------------------------
// fp32-accurate MFMA GEMM (NT): C[m,n] = sum_k A[m,k] * W[n,k].
// fp32 inputs loaded from global, split to bf16 hi/lo in-register, 3 MFMA
// passes (hh + hl + lh) recover ~fp32 accuracy. No LDS.
// Block: 256 thr = 4 waves, 64x64 tile; wave = 32x32 = 2x2 of 16x16x32 mfma.
// A-frag: m=lane&15, k=(lane>>4)*8+j.  C/D: col=lane&15, row=(lane>>4)*4+reg.
// ---------------------------------------------------------------------------
__global__ __launch_bounds__(256) void gemm_mfma_f32(
    const float* __restrict__ A, const float* __restrict__ W,
    float* __restrict__ C, int Mdim, int Ndim, int Kdim)
{
    const int t = threadIdx.x;
    const int wave = t >> 6, lane = t & 63;
    const int r = lane & 15, qd = lane >> 4;
    const int m0 = blockIdx.x * 64 + (wave & 1) * 32;
    const int n0 = blockIdx.y * 64 + (wave >> 1) * 32;

    f32x4 acc[2][2];
#pragma unroll
    for (int i = 0; i < 2; ++i)
#pragma unroll
        for (int j = 0; j < 2; ++j) acc[i][j] = (f32x4){0.f, 0.f, 0.f, 0.f};

    const float* pa0 = A + (size_t)(m0 + r) * Kdim + qd * 8;
    const float* pa1 = pa0 + (size_t)16 * Kdim;
    const float* pb0 = W + (size_t)(n0 + r) * Kdim + qd * 8;
    const float* pb1 = pb0 + (size_t)16 * Kdim;

    for (int k0 = 0; k0 < Kdim; k0 += 32) {
        bf16x8 ah0, al0, ah1, al1, bh0, bl0, bh1, bl1;
        load_frag_split(pa0 + k0, ah0, al0);
        load_frag_split(pa1 + k0, ah1, al1);
        load_frag_split(pb0 + k0, bh0, bl0);
        load_frag_split(pb1 + k0, bh1, bl1);

        acc[0][0] = __builtin_amdgcn_mfma_f32_16x16x32_bf16(ah0, bh0, acc[0][0], 0, 0, 0);
        acc[0][1] = __builtin_amdgcn_mfma_f32_16x16x32_bf16(ah0, bh1, acc[0][1], 0, 0, 0);
        acc[1][0] = __builtin_amdgcn_mfma_f32_16x16x32_bf16(ah1, bh0, acc[1][0], 0, 0, 0);
        acc[1][1] = __builtin_amdgcn_mfma_f32_16x16x32_bf16(ah1, bh1, acc[1][1], 0, 0, 0);

        acc[0][0] = __builtin_amdgcn_mfma_f32_16x16x32_bf16(ah0, bl0, acc[0][0], 0, 0, 0);
        acc[0][1] = __builtin_amdgcn_mfma_f32_16x16x32_bf16(ah0, bl1, acc[0][1], 0, 0, 0);
        acc[1][0] = __builtin_amdgcn_mfma_f32_16x16x32_bf16(ah1, bl0, acc[1][0], 0, 0, 0);
        acc[1][1] = __builtin_amdgcn_mfma_f32_16x16x32_bf16(ah1, bl1, acc[1][1], 0, 0, 0);

        acc[0][0] = __builtin_amdgcn_mfma_f32_16x16x32_bf16(al0, bh0, acc[0][0], 0, 0, 0);
        acc[0][1] = __builtin_amdgcn_mfma_f32_16x16x32_bf16(al0, bh1, acc[0][1], 0, 0, 0);
        acc[1][0] = __builtin_amdgcn_mfma_f32_16x16x32_bf16(al1, bh0, acc[1][0], 0, 0, 0);
        acc[1][1] = __builtin_amdgcn_mfma_f32_16x16x32_bf16(al1, bh1, acc[1][1], 0, 0, 0);
    }

#pragma unroll
    for (int mt = 0; mt < 2; ++mt)
#pragma unroll
        for (int nt = 0; nt < 2; ++nt)
#pragma unroll
            for (int rr = 0; rr < 4; ++rr)
                C[(size_t)(m0 + mt * 16 + qd * 4 + rr) * Ndim + n0 + nt * 16 + r] =
                    acc[mt][nt][rr];
}

// ---------------------------------------------------------------------------
// Attention: one wave per (b,h,i) query. float4 gather: lane l = 16*grp+sub
// loads 16B of row (4g+grp); one wave-load fetches 4 rows (1KB).
// MASK-PREDICATED GATHER: masked neighbors' k rows are never needed (sim is
// overwritten with -FLT_MAX); their v rows only matter in the all-masked
// case (jax softmax -> uniform 1/32). Skipping those loads via exec-mask
// predication halves the random-gather traffic on the L2-miss path.
// ---------------------------------------------------------------------------
__global__ __launch_bounds__(256) void attn_kernel(
    const float* __restrict__ qbuf,       // [b*n][512]
    const float* __restrict__ mem_db,     // [b][M][128]
    const int* __restrict__ knn_idx,      // [b][h][n][K]
    const void* __restrict__ mem_mask,    // [b][h][n][K] bool-or-int32
    const float* __restrict__ scale_param,// [h]
    const int* __restrict__ flag,
    float* __restrict__ outbuf)           // [b*n][512]
{
    const int wave = blockIdx.x * 4 + (threadIdx.x >> 6);
    const int lane = threadIdx.x & 63;
    const int sub = lane & 15, grp = lane >> 4;
    const int i = wave % N_SEQ;
    const int bh = wave / N_SEQ;
    const int hi = bh % H_HEADS;
    const int bi = bh / H_HEADS;

    const int bytelayout = *flag;  // uniform

    const float* qrow = qbuf + (size_t)(bi * N_SEQ + i) * DIM + hi * D_HEAD;
    float qv = qrow[lane];
    float ss = qv * qv;
#pragma unroll
    for (int s = 32; s; s >>= 1) ss += __shfl_xor(ss, s);
    qv = qv / fmaxf(sqrtf(ss), 1e-12f);

    // q in float4-per-lane layout: q4[c] = q[4*sub + c]
    float q4[4];
#pragma unroll
    for (int c = 0; c < 4; ++c) q4[c] = __shfl(qv, 4 * sub + c);

    const float scale = __expf(scale_param[hi]);

    const size_t kb = ((size_t)(bi * H_HEADS + hi) * N_SEQ + i) * K_NN;
    int idxv = 0, maskv = 0;
    if (lane < K_NN) {
        idxv = knn_idx[kb + lane];
        if (bytelayout)
            maskv = ((const unsigned char*)mem_mask)[kb + lane] ? 1 : 0;
        else
            maskv = ((const int*)mem_mask)[kb + lane] ? 1 : 0;
    }

    // Wave-uniform mask bitmap (bits 0..31); uniform within each 16-lane grp.
    unsigned long long mbits = __ballot(maskv != 0);
    const bool allmasked = (mbits == 0ull);

    const float* dbb = mem_db + (size_t)bi * M_DB * (2 * D_HEAD);

    // Gather: group g covers rows 4g..4g+3; my row = 4g+grp, my 16B = [4*sub..]
    // k loaded only if row unmasked; v if unmasked or all-masked.
    float4 kk[8], vv[8];
#pragma unroll
    for (int g = 0; g < 8; ++g) {
        int idx = __shfl(idxv, 4 * g + grp);
        bool mrow = (mbits >> (4 * g + grp)) & 1ull;
        const float* row = dbb + (size_t)idx * (2 * D_HEAD);
        kk[g] = (float4){0.f, 0.f, 0.f, 0.f};
        vv[g] = (float4){0.f, 0.f, 0.f, 0.f};
        if (mrow)
            kk[g] = *(const float4*)(row + 4 * sub);
        if (mrow || allmasked)
            vv[g] = *(const float4*)(row + D_HEAD + 4 * sub);
    }

    // Dot products: 4-elem partial per lane, 4-step butterfly over 16 lanes
    float s8[8];
#pragma unroll
    for (int g = 0; g < 8; ++g) {
        float p = q4[0] * kk[g].x + q4[1] * kk[g].y + q4[2] * kk[g].z + q4[3] * kk[g].w;
        p += __shfl_xor(p, 1);
        p += __shfl_xor(p, 2);
        p += __shfl_xor(p, 4);
        p += __shfl_xor(p, 8);
        s8[g] = p;  // full dot of row 4g+grp (replicated in 16-lane group)
    }

    // Collect: lane j<32 takes s8[j>>2] from source lane (j&3)<<4
    float simlane = -INFINITY;
#pragma unroll
    for (int g = 0; g < 8; ++g) {
        float tv = __shfl(s8[g], (lane & 3) << 4);
        if ((lane >> 2) == g) simlane = tv;  // lanes>=32 never match: stay -inf
    }
    if (lane < K_NN)
        simlane = maskv ? simlane * scale : -3.402823466e38f;

    // Softmax across 64 lanes
    float m = simlane;
#pragma unroll
    for (int s = 32; s; s >>= 1) m = fmaxf(m, __shfl_xor(m, s));
    float w = __expf(simlane - m);
    float l = w;
#pragma unroll
    for (int s = 32; s; s >>= 1) l += __shfl_xor(l, s);
    float winv = w / l;

    // Weighted sum of V (float4 layout), then reduce across the 4 groups
    float4 o = {0.f, 0.f, 0.f, 0.f};
#pragma unroll
    for (int g = 0; g < 8; ++g) {
        float wg = __shfl(winv, 4 * g + grp);
        o.x = fmaf(wg, vv[g].x, o.x);
        o.y = fmaf(wg, vv[g].y, o.y);
        o.z = fmaf(wg, vv[g].z, o.z);
        o.w = fmaf(wg, vv[g].w, o.w);
    }
#pragma unroll
    for (int s = 16; s <= 32; s <<= 1) {
        o.x += __shfl_xor(o.x, s);
        o.y += __shfl_xor(o.y, s);
        o.z += __shfl_xor(o.z, s);
        o.w += __shfl_xor(o.w, s);
    }
    if (grp == 0)
        *(float4*)(outbuf + (size_t)(bi * N_SEQ + i) * DIM + hi * D_HEAD + 4 * sub) = o;
}

// ---------------------------------------------------------------------------
extern "C" void kernel_launch(void* const* d_in, const int* in_sizes, int n_in,
                              void* d_out, int out_size, void* d_ws, size_t ws_size,
                              hipStream_t stream) {
    const float* x        = (const float*)d_in[0];
    const float* mem_db   = (const float*)d_in[1];
    const int*   knn_idx  = (const int*)d_in[2];
    const void*  mem_mask = d_in[3];
    const float* Wq       = (const float*)d_in[4];
    // d_in[5] = Wkv: dead code in the reference, unused.
    const float* Wout     = (const float*)d_in[6];
    const float* scale_p  = (const float*)d_in[7];
    float* out = (float*)d_out;

    const int Mrows = B_SZ * N_SEQ;  // 4096
    const int n_x   = Mrows * DIM;   // 2097152

    // Workspace: flag | qbuf (8MB) | attn_out (8MB)
    char* ws = (char*)d_ws;
    int* flag = (int*)ws;
    float* qbuf     = (float*)(ws + 256);
    float* attn_out = qbuf + (size_t)n_x;

    detect_mask_layout<<<1, 64, 0, stream>>>((const unsigned char*)mem_mask, flag);

    dim3 ggrid(Mrows / 64, DIM / 64);  // (64, 8)
    gemm_mfma_f32<<<ggrid, 256, 0, stream>>>(x, Wq, qbuf, Mrows, DIM, DIM);

    const int n_waves = B_SZ * H_HEADS * N_SEQ;  // 32768
    attn_kernel<<<n_waves / 4, 256, 0, stream>>>(qbuf, mem_db, knn_idx, mem_mask,
                                                 scale_p, flag, attn_out);

    gemm_mfma_f32<<<ggrid, 256, 0, stream>>>(attn_out, Wout, out, Mrows, DIM, DIM);
}

// Round 5
// 288.786 us; speedup vs baseline: 1.2681x; 1.0011x over previous
//
#include <hip/hip_runtime.h>
#include <hip/hip_bf16.h>
#include <math.h>

// Problem constants (fixed by setup_inputs)
#define B_SZ 2
#define N_SEQ 2048
#define DIM 512
#define H_HEADS 8
#define D_HEAD 64
#define K_NN 32
#define M_DB 131072

typedef __attribute__((ext_vector_type(8))) short bf16x8;
typedef __attribute__((ext_vector_type(4))) float f32x4;

// ---------------------------------------------------------------------------
// Mask-layout detection (numpy bool may arrive as 1-byte or widened int32).
// ---------------------------------------------------------------------------
__global__ void detect_mask_layout(const unsigned char* __restrict__ mb,
                                   int* __restrict__ flag) {
    int t = threadIdx.x;  // 64 threads
    unsigned char v = 0;
    for (int e = t; e < 1024; e += 64) {
        v |= mb[4 * e + 1];
        v |= mb[4 * e + 2];
        v |= mb[4 * e + 3];
    }
    unsigned long long any = __ballot(v != 0);
    if (t == 0) *flag = (any != 0ull) ? 1 : 0;  // 1 = byte layout, 0 = int32
}

// ---------------------------------------------------------------------------
// fp32 -> (hi, lo) bf16 split. f ~= hi + lo to ~2^-17 relative.
// ---------------------------------------------------------------------------
__device__ __forceinline__ void cvt_hi_lo(float f, short& h, short& l) {
    unsigned u = __float_as_uint(f);
    unsigned uh = u + (0x7fffu + ((u >> 16) & 1u));
    h = (short)(uh >> 16);
    float r = f - __uint_as_float((uh >> 16) << 16);
    unsigned ur = __float_as_uint(r);
    l = (short)((ur + (0x7fffu + ((ur >> 16) & 1u))) >> 16);
}

__device__ __forceinline__ void load_frag_split(const float* __restrict__ p,
                                                bf16x8& h, bf16x8& l) {
    float4 f0 = *(const float4*)p;
    float4 f1 = *(const float4*)(p + 4);
    float ff[8] = {f0.x, f0.y, f0.z, f0.w, f1.x, f1.y, f1.z, f1.w};
#pragma unroll
    for (int e = 0; e < 8; ++e) {
        short hh, ll;
        cvt_hi_lo(ff[e], hh, ll);
        h[e] = hh; l[e] = ll;
    }
}

// Split both weight matrices (DIM*DIM each) into bf16 hi/lo planes.
__global__ __launch_bounds__(256) void split_weights(
    const float4* __restrict__ wq, const float4* __restrict__ wout,
    ushort4* __restrict__ qhi, ushort4* __restrict__ qlo,
    ushort4* __restrict__ ohi, ushort4* __restrict__ olo) {
    const int n4 = DIM * DIM / 4;  // 65536 float4s per weight
    int i = blockIdx.x * 256 + threadIdx.x;
    const float4* src = (i < n4) ? wq : wout;
    ushort4* dh = (i < n4) ? qhi : ohi;
    ushort4* dl = (i < n4) ? qlo : olo;
    int j = (i < n4) ? i : i - n4;
    float4 a = src[j];
    ushort4 h, l;
    short hh, ll;
    cvt_hi_lo(a.x, hh, ll); h.x = hh; l.x = ll;
    cvt_hi_lo(a.y, hh, ll); h.y = hh; l.y = ll;
    cvt_hi_lo(a.z, hh, ll); h.z = hh; l.z = ll;
    cvt_hi_lo(a.w, hh, ll); h.w = hh; l.w = ll;
    dh[j] = h; dl[j] = l;
}

// ---------------------------------------------------------------------------
// fp32-accurate MFMA GEMM (NT): C[m,n] = sum_k A[m,k] * W[n,k].
// A fp32 (split in-register); W pre-split bf16 hi/lo planes. 3 MFMA passes
// (hh + hl + lh) recover ~fp32 accuracy. No LDS.
// Block: 256 thr = 4 waves, 64x64 tile; wave = 32x32 = 2x2 of 16x16x32 mfma.
// A-frag: m=lane&15, k=(lane>>4)*8+j.  C/D: col=lane&15, row=(lane>>4)*4+reg.
// ---------------------------------------------------------------------------
__global__ __launch_bounds__(256) void gemm_mfma_f32(
    const float* __restrict__ A,
    const unsigned short* __restrict__ Bhi, const unsigned short* __restrict__ Blo,
    float* __restrict__ C, int Mdim, int Ndim, int Kdim)
{
    const int t = threadIdx.x;
    const int wave = t >> 6, lane = t & 63;
    const int r = lane & 15, qd = lane >> 4;
    const int m0 = blockIdx.x * 64 + (wave & 1) * 32;
    const int n0 = blockIdx.y * 64 + (wave >> 1) * 32;

    f32x4 acc[2][2];
#pragma unroll
    for (int i = 0; i < 2; ++i)
#pragma unroll
        for (int j = 0; j < 2; ++j) acc[i][j] = (f32x4){0.f, 0.f, 0.f, 0.f};

    const float* pa0 = A + (size_t)(m0 + r) * Kdim + qd * 8;
    const float* pa1 = pa0 + (size_t)16 * Kdim;
    const size_t b0 = (size_t)(n0 + r) * Kdim + qd * 8;
    const size_t b1 = b0 + (size_t)16 * Kdim;

    for (int k0 = 0; k0 < Kdim; k0 += 32) {
        bf16x8 ah0, al0, ah1, al1;
        load_frag_split(pa0 + k0, ah0, al0);
        load_frag_split(pa1 + k0, ah1, al1);
        bf16x8 bh0 = *(const bf16x8*)(Bhi + b0 + k0);
        bf16x8 bh1 = *(const bf16x8*)(Bhi + b1 + k0);
        bf16x8 bl0 = *(const bf16x8*)(Blo + b0 + k0);
        bf16x8 bl1 = *(const bf16x8*)(Blo + b1 + k0);

        acc[0][0] = __builtin_amdgcn_mfma_f32_16x16x32_bf16(ah0, bh0, acc[0][0], 0, 0, 0);
        acc[0][1] = __builtin_amdgcn_mfma_f32_16x16x32_bf16(ah0, bh1, acc[0][1], 0, 0, 0);
        acc[1][0] = __builtin_amdgcn_mfma_f32_16x16x32_bf16(ah1, bh0, acc[1][0], 0, 0, 0);
        acc[1][1] = __builtin_amdgcn_mfma_f32_16x16x32_bf16(ah1, bh1, acc[1][1], 0, 0, 0);

        acc[0][0] = __builtin_amdgcn_mfma_f32_16x16x32_bf16(ah0, bl0, acc[0][0], 0, 0, 0);
        acc[0][1] = __builtin_amdgcn_mfma_f32_16x16x32_bf16(ah0, bl1, acc[0][1], 0, 0, 0);
        acc[1][0] = __builtin_amdgcn_mfma_f32_16x16x32_bf16(ah1, bl0, acc[1][0], 0, 0, 0);
        acc[1][1] = __builtin_amdgcn_mfma_f32_16x16x32_bf16(ah1, bl1, acc[1][1], 0, 0, 0);

        acc[0][0] = __builtin_amdgcn_mfma_f32_16x16x32_bf16(al0, bh0, acc[0][0], 0, 0, 0);
        acc[0][1] = __builtin_amdgcn_mfma_f32_16x16x32_bf16(al0, bh1, acc[0][1], 0, 0, 0);
        acc[1][0] = __builtin_amdgcn_mfma_f32_16x16x32_bf16(al1, bh0, acc[1][0], 0, 0, 0);
        acc[1][1] = __builtin_amdgcn_mfma_f32_16x16x32_bf16(al1, bh1, acc[1][1], 0, 0, 0);
    }

#pragma unroll
    for (int mt = 0; mt < 2; ++mt)
#pragma unroll
        for (int nt = 0; nt < 2; ++nt)
#pragma unroll
            for (int rr = 0; rr < 4; ++rr)
                C[(size_t)(m0 + mt * 16 + qd * 4 + rr) * Ndim + n0 + nt * 16 + r] =
                    acc[mt][nt][rr];
}

// ---------------------------------------------------------------------------
// Attention: one wave per (b,h,i) query. float4 gather: lane l = 16*grp+sub
// loads 16B of row (4g+grp); one wave-load fetches 4 rows (1KB).
// MASK-PREDICATION VIA ADDRESS SELECT (no branches): masked rows read from a
// dummy L2-hot row (row 0). Garbage k values feed sims that are overwritten
// with -FLT_MAX; garbage v values get softmax weight exactly 0. All-masked
// case (jax uniform 1/32) selects real v addresses. Loads always issue =>
// maximum memory-level parallelism, halved random-gather bytes.
// ---------------------------------------------------------------------------
__global__ __launch_bounds__(256) void attn_kernel(
    const float* __restrict__ qbuf,       // [b*n][512]
    const float* __restrict__ mem_db,     // [b][M][128]
    const int* __restrict__ knn_idx,      // [b][h][n][K]
    const void* __restrict__ mem_mask,    // [b][h][n][K] bool-or-int32
    const float* __restrict__ scale_param,// [h]
    const int* __restrict__ flag,
    float* __restrict__ outbuf)           // [b*n][512]
{
    const int wave = blockIdx.x * 4 + (threadIdx.x >> 6);
    const int lane = threadIdx.x & 63;
    const int sub = lane & 15, grp = lane >> 4;
    const int i = wave % N_SEQ;
    const int bh = wave / N_SEQ;
    const int hi = bh % H_HEADS;
    const int bi = bh / H_HEADS;

    const int bytelayout = *flag;  // uniform

    const float* qrow = qbuf + (size_t)(bi * N_SEQ + i) * DIM + hi * D_HEAD;
    float qv = qrow[lane];
    float ss = qv * qv;
#pragma unroll
    for (int s = 32; s; s >>= 1) ss += __shfl_xor(ss, s);
    qv = qv / fmaxf(sqrtf(ss), 1e-12f);

    // q in float4-per-lane layout: q4[c] = q[4*sub + c]
    float q4[4];
#pragma unroll
    for (int c = 0; c < 4; ++c) q4[c] = __shfl(qv, 4 * sub + c);

    const float scale = __expf(scale_param[hi]);

    const size_t kb = ((size_t)(bi * H_HEADS + hi) * N_SEQ + i) * K_NN;
    int idxv = 0, maskv = 0;
    if (lane < K_NN) {
        idxv = knn_idx[kb + lane];
        if (bytelayout)
            maskv = ((const unsigned char*)mem_mask)[kb + lane] ? 1 : 0;
        else
            maskv = ((const int*)mem_mask)[kb + lane] ? 1 : 0;
    }

    // Wave-uniform mask bitmap (bits 0..31); uniform within each 16-lane grp.
    unsigned long long mbits = __ballot(maskv != 0);
    const bool allmasked = (mbits == 0ull);

    const float* dbb = mem_db + (size_t)bi * M_DB * (2 * D_HEAD);

    // Gather: group g covers rows 4g..4g+3; my row = 4g+grp, my 16B = [4*sub..]
    // Address-select: masked rows read dummy row 0 (L2-hot), always issue.
    float4 kk[8], vv[8];
#pragma unroll
    for (int g = 0; g < 8; ++g) {
        int idx = __shfl(idxv, 4 * g + grp);
        bool mrow = (mbits >> (4 * g + grp)) & 1ull;
        size_t koff = mrow ? (size_t)idx * (2 * D_HEAD) : 0;
        size_t voff = (mrow || allmasked) ? (size_t)idx * (2 * D_HEAD) : 0;
        kk[g] = *(const float4*)(dbb + koff + 4 * sub);
        vv[g] = *(const float4*)(dbb + voff + D_HEAD + 4 * sub);
    }

    // Dot products: 4-elem partial per lane, 4-step butterfly over 16 lanes
    float s8[8];
#pragma unroll
    for (int g = 0; g < 8; ++g) {
        float p = q4[0] * kk[g].x + q4[1] * kk[g].y + q4[2] * kk[g].z + q4[3] * kk[g].w;
        p += __shfl_xor(p, 1);
        p += __shfl_xor(p, 2);
        p += __shfl_xor(p, 4);
        p += __shfl_xor(p, 8);
        s8[g] = p;  // full dot of row 4g+grp (replicated in 16-lane group)
    }

    // Collect: lane j<32 takes s8[j>>2] from source lane (j&3)<<4
    float simlane = -INFINITY;
#pragma unroll
    for (int g = 0; g < 8; ++g) {
        float tv = __shfl(s8[g], (lane & 3) << 4);
        if ((lane >> 2) == g) simlane = tv;  // lanes>=32 never match: stay -inf
    }
    if (lane < K_NN)
        simlane = maskv ? simlane * scale : -3.402823466e38f;

    // Softmax across 64 lanes
    float m = simlane;
#pragma unroll
    for (int s = 32; s; s >>= 1) m = fmaxf(m, __shfl_xor(m, s));
    float w = __expf(simlane - m);
    float l = w;
#pragma unroll
    for (int s = 32; s; s >>= 1) l += __shfl_xor(l, s);
    float winv = w / l;

    // Weighted sum of V (float4 layout), then reduce across the 4 groups
    float4 o = {0.f, 0.f, 0.f, 0.f};
#pragma unroll
    for (int g = 0; g < 8; ++g) {
        float wg = __shfl(winv, 4 * g + grp);
        o.x = fmaf(wg, vv[g].x, o.x);
        o.y = fmaf(wg, vv[g].y, o.y);
        o.z = fmaf(wg, vv[g].z, o.z);
        o.w = fmaf(wg, vv[g].w, o.w);
    }
#pragma unroll
    for (int s = 16; s <= 32; s <<= 1) {
        o.x += __shfl_xor(o.x, s);
        o.y += __shfl_xor(o.y, s);
        o.z += __shfl_xor(o.z, s);
        o.w += __shfl_xor(o.w, s);
    }
    if (grp == 0)
        *(float4*)(outbuf + (size_t)(bi * N_SEQ + i) * DIM + hi * D_HEAD + 4 * sub) = o;
}

// ---------------------------------------------------------------------------
extern "C" void kernel_launch(void* const* d_in, const int* in_sizes, int n_in,
                              void* d_out, int out_size, void* d_ws, size_t ws_size,
                              hipStream_t stream) {
    const float* x        = (const float*)d_in[0];
    const float* mem_db   = (const float*)d_in[1];
    const int*   knn_idx  = (const int*)d_in[2];
    const void*  mem_mask = d_in[3];
    const float* Wq       = (const float*)d_in[4];
    // d_in[5] = Wkv: dead code in the reference, unused.
    const float* Wout     = (const float*)d_in[6];
    const float* scale_p  = (const float*)d_in[7];
    float* out = (float*)d_out;

    const int Mrows = B_SZ * N_SEQ;  // 4096
    const int n_x   = Mrows * DIM;   // 2097152
    const int n_w   = DIM * DIM;     // 262144

    // Workspace: flag | qbuf (8MB) | attn_out (8MB) | 4 weight planes (2MB)
    char* ws = (char*)d_ws;
    int* flag = (int*)ws;
    float* qbuf     = (float*)(ws + 256);
    float* attn_out = qbuf + (size_t)n_x;
    unsigned short* wq_hi = (unsigned short*)(attn_out + (size_t)n_x);
    unsigned short* wq_lo = wq_hi + n_w;
    unsigned short* wo_hi = wq_lo + n_w;
    unsigned short* wo_lo = wo_hi + n_w;

    detect_mask_layout<<<1, 64, 0, stream>>>((const unsigned char*)mem_mask, flag);
    split_weights<<<2 * n_w / 1024, 256, 0, stream>>>(
        (const float4*)Wq, (const float4*)Wout,
        (ushort4*)wq_hi, (ushort4*)wq_lo, (ushort4*)wo_hi, (ushort4*)wo_lo);

    dim3 ggrid(Mrows / 64, DIM / 64);  // (64, 8)
    gemm_mfma_f32<<<ggrid, 256, 0, stream>>>(x, wq_hi, wq_lo, qbuf, Mrows, DIM, DIM);

    const int n_waves = B_SZ * H_HEADS * N_SEQ;  // 32768
    attn_kernel<<<n_waves / 4, 256, 0, stream>>>(qbuf, mem_db, knn_idx, mem_mask,
                                                 scale_p, flag, attn_out);

    gemm_mfma_f32<<<ggrid, 256, 0, stream>>>(attn_out, wo_hi, wo_lo, out, Mrows, DIM, DIM);
}

// Round 6
// 287.608 us; speedup vs baseline: 1.2733x; 1.0041x over previous
//
#include <hip/hip_runtime.h>
#include <hip/hip_bf16.h>
#include <math.h>

// Problem constants (fixed by setup_inputs)
#define B_SZ 2
#define N_SEQ 2048
#define DIM 512
#define H_HEADS 8
#define D_HEAD 64
#define K_NN 32
#define M_DB 131072

typedef __attribute__((ext_vector_type(8))) short bf16x8;
typedef __attribute__((ext_vector_type(4))) float f32x4;

// ---------------------------------------------------------------------------
// fp32 -> (hi, lo) bf16 split. f ~= hi + lo to ~2^-17 relative.
// ---------------------------------------------------------------------------
__device__ __forceinline__ void cvt_hi_lo(float f, short& h, short& l) {
    unsigned u = __float_as_uint(f);
    unsigned uh = u + (0x7fffu + ((u >> 16) & 1u));
    h = (short)(uh >> 16);
    float r = f - __uint_as_float((uh >> 16) << 16);
    unsigned ur = __float_as_uint(r);
    l = (short)((ur + (0x7fffu + ((ur >> 16) & 1u))) >> 16);
}

__device__ __forceinline__ void split4(float4 a, ushort4& h, ushort4& l) {
    short hh, ll;
    cvt_hi_lo(a.x, hh, ll); h.x = hh; l.x = ll;
    cvt_hi_lo(a.y, hh, ll); h.y = hh; l.y = ll;
    cvt_hi_lo(a.z, hh, ll); h.z = hh; l.z = ll;
    cvt_hi_lo(a.w, hh, ll); h.w = hh; l.w = ll;
}

// ---------------------------------------------------------------------------
// Fused prep: split x (2048 blocks) + Wq/Wout (512 blocks) into bf16 hi/lo
// planes, and detect mask layout (1 block). One dispatch.
// ---------------------------------------------------------------------------
__global__ __launch_bounds__(256) void prep_kernel(
    const float4* __restrict__ x, const float4* __restrict__ wq,
    const float4* __restrict__ wout,
    ushort4* __restrict__ xhi, ushort4* __restrict__ xlo,
    ushort4* __restrict__ qhi, ushort4* __restrict__ qlo,
    ushort4* __restrict__ ohi, ushort4* __restrict__ olo,
    const unsigned char* __restrict__ mb, int* __restrict__ flag)
{
    const int bid = blockIdx.x;
    const int t = threadIdx.x;
    if (bid < 2048) {                       // x: 524288 float4s
        int i = bid * 256 + t;
        ushort4 h, l;
        split4(x[i], h, l);
        xhi[i] = h; xlo[i] = l;
    } else if (bid < 2560) {                // weights: 2*65536 float4s
        int i = (bid - 2048) * 256 + t;
        const int n4 = DIM * DIM / 4;       // 65536
        const float4* src = (i < n4) ? wq : wout;
        ushort4* dh = (i < n4) ? qhi : ohi;
        ushort4* dl = (i < n4) ? qlo : olo;
        int j = (i < n4) ? i : i - n4;
        ushort4 h, l;
        split4(src[j], h, l);
        dh[j] = h; dl[j] = l;
    } else {                                // mask-layout detect (64 lanes act)
        if (t < 64) {
            unsigned char v = 0;
            for (int e = t; e < 1024; e += 64) {
                v |= mb[4 * e + 1];
                v |= mb[4 * e + 2];
                v |= mb[4 * e + 3];
            }
            unsigned long long any = __ballot(v != 0);
            if (t == 0) *flag = (any != 0ull) ? 1 : 0;  // 1 = byte layout
        }
    }
}

// ---------------------------------------------------------------------------
// fp32-accurate MFMA GEMM (NT) on pre-split bf16 planes:
// C[m,n] = sum_k A[m,k]*W[n,k], 3 passes (hh + hl + lh) ~= fp32. No LDS,
// no in-loop converts: K-loop = 8 dwordx4 loads + 12 MFMA.
// Block: 256 thr = 4 waves, 64x64 tile; wave = 32x32 = 2x2 of 16x16x32 mfma.
// A-frag: m=lane&15, k=(lane>>4)*8+j.  C/D: col=lane&15, row=(lane>>4)*4+reg.
// ---------------------------------------------------------------------------
__global__ __launch_bounds__(256) void gemm_mfma_planes(
    const unsigned short* __restrict__ Ahi, const unsigned short* __restrict__ Alo,
    const unsigned short* __restrict__ Bhi, const unsigned short* __restrict__ Blo,
    float* __restrict__ C, int Mdim, int Ndim, int Kdim)
{
    const int t = threadIdx.x;
    const int wave = t >> 6, lane = t & 63;
    const int r = lane & 15, qd = lane >> 4;
    const int m0 = blockIdx.x * 64 + (wave & 1) * 32;
    const int n0 = blockIdx.y * 64 + (wave >> 1) * 32;

    f32x4 acc[2][2];
#pragma unroll
    for (int i = 0; i < 2; ++i)
#pragma unroll
        for (int j = 0; j < 2; ++j) acc[i][j] = (f32x4){0.f, 0.f, 0.f, 0.f};

    const size_t a0 = (size_t)(m0 + r) * Kdim + qd * 8;
    const size_t a1 = a0 + (size_t)16 * Kdim;
    const size_t b0 = (size_t)(n0 + r) * Kdim + qd * 8;
    const size_t b1 = b0 + (size_t)16 * Kdim;

    for (int k0 = 0; k0 < Kdim; k0 += 32) {
        bf16x8 ah0 = *(const bf16x8*)(Ahi + a0 + k0);
        bf16x8 ah1 = *(const bf16x8*)(Ahi + a1 + k0);
        bf16x8 al0 = *(const bf16x8*)(Alo + a0 + k0);
        bf16x8 al1 = *(const bf16x8*)(Alo + a1 + k0);
        bf16x8 bh0 = *(const bf16x8*)(Bhi + b0 + k0);
        bf16x8 bh1 = *(const bf16x8*)(Bhi + b1 + k0);
        bf16x8 bl0 = *(const bf16x8*)(Blo + b0 + k0);
        bf16x8 bl1 = *(const bf16x8*)(Blo + b1 + k0);

        acc[0][0] = __builtin_amdgcn_mfma_f32_16x16x32_bf16(ah0, bh0, acc[0][0], 0, 0, 0);
        acc[0][1] = __builtin_amdgcn_mfma_f32_16x16x32_bf16(ah0, bh1, acc[0][1], 0, 0, 0);
        acc[1][0] = __builtin_amdgcn_mfma_f32_16x16x32_bf16(ah1, bh0, acc[1][0], 0, 0, 0);
        acc[1][1] = __builtin_amdgcn_mfma_f32_16x16x32_bf16(ah1, bh1, acc[1][1], 0, 0, 0);

        acc[0][0] = __builtin_amdgcn_mfma_f32_16x16x32_bf16(ah0, bl0, acc[0][0], 0, 0, 0);
        acc[0][1] = __builtin_amdgcn_mfma_f32_16x16x32_bf16(ah0, bl1, acc[0][1], 0, 0, 0);
        acc[1][0] = __builtin_amdgcn_mfma_f32_16x16x32_bf16(ah1, bl0, acc[1][0], 0, 0, 0);
        acc[1][1] = __builtin_amdgcn_mfma_f32_16x16x32_bf16(ah1, bl1, acc[1][1], 0, 0, 0);

        acc[0][0] = __builtin_amdgcn_mfma_f32_16x16x32_bf16(al0, bh0, acc[0][0], 0, 0, 0);
        acc[0][1] = __builtin_amdgcn_mfma_f32_16x16x32_bf16(al0, bh1, acc[0][1], 0, 0, 0);
        acc[1][0] = __builtin_amdgcn_mfma_f32_16x16x32_bf16(al1, bh0, acc[1][0], 0, 0, 0);
        acc[1][1] = __builtin_amdgcn_mfma_f32_16x16x32_bf16(al1, bh1, acc[1][1], 0, 0, 0);
    }

#pragma unroll
    for (int mt = 0; mt < 2; ++mt)
#pragma unroll
        for (int nt = 0; nt < 2; ++nt)
#pragma unroll
            for (int rr = 0; rr < 4; ++rr)
                C[(size_t)(m0 + mt * 16 + qd * 4 + rr) * Ndim + n0 + nt * 16 + r] =
                    acc[mt][nt][rr];
}

// ---------------------------------------------------------------------------
// Attention: one wave per (b,h,i) query. float4 gather: lane l = 16*grp+sub
// loads 16B of row (4g+grp); one wave-load fetches 4 rows (1KB).
// Mask-predicated via address select (masked rows -> L2-hot row 0; garbage
// values annihilated by -FLT_MAX / zero softmax weight; all-masked case uses
// real v addresses -> jax uniform 1/32). Output written as pre-split bf16
// hi/lo planes so the out-projection GEMM needs no in-loop converts.
// ---------------------------------------------------------------------------
__global__ __launch_bounds__(256) void attn_kernel(
    const float* __restrict__ qbuf,       // [b*n][512] fp32
    const float* __restrict__ mem_db,     // [b][M][128]
    const int* __restrict__ knn_idx,      // [b][h][n][K]
    const void* __restrict__ mem_mask,    // [b][h][n][K] bool-or-int32
    const float* __restrict__ scale_param,// [h]
    const int* __restrict__ flag,
    unsigned short* __restrict__ out_hi,  // [b*n][512] bf16 hi plane
    unsigned short* __restrict__ out_lo)  // [b*n][512] bf16 lo plane
{
    const int wave = blockIdx.x * 4 + (threadIdx.x >> 6);
    const int lane = threadIdx.x & 63;
    const int sub = lane & 15, grp = lane >> 4;
    const int i = wave % N_SEQ;
    const int bh = wave / N_SEQ;
    const int hi = bh % H_HEADS;
    const int bi = bh / H_HEADS;

    const int bytelayout = *flag;  // uniform

    const float* qrow = qbuf + (size_t)(bi * N_SEQ + i) * DIM + hi * D_HEAD;
    float qv = qrow[lane];
    float ss = qv * qv;
#pragma unroll
    for (int s = 32; s; s >>= 1) ss += __shfl_xor(ss, s);
    qv = qv / fmaxf(sqrtf(ss), 1e-12f);

    // q in float4-per-lane layout: q4[c] = q[4*sub + c]
    float q4[4];
#pragma unroll
    for (int c = 0; c < 4; ++c) q4[c] = __shfl(qv, 4 * sub + c);

    const float scale = __expf(scale_param[hi]);

    const size_t kb = ((size_t)(bi * H_HEADS + hi) * N_SEQ + i) * K_NN;
    int idxv = 0, maskv = 0;
    if (lane < K_NN) {
        idxv = knn_idx[kb + lane];
        if (bytelayout)
            maskv = ((const unsigned char*)mem_mask)[kb + lane] ? 1 : 0;
        else
            maskv = ((const int*)mem_mask)[kb + lane] ? 1 : 0;
    }

    unsigned long long mbits = __ballot(maskv != 0);
    const bool allmasked = (mbits == 0ull);

    const float* dbb = mem_db + (size_t)bi * M_DB * (2 * D_HEAD);

    // Gather: group g covers rows 4g..4g+3; my row = 4g+grp, my 16B = [4*sub..]
    float4 kk[8], vv[8];
#pragma unroll
    for (int g = 0; g < 8; ++g) {
        int idx = __shfl(idxv, 4 * g + grp);
        bool mrow = (mbits >> (4 * g + grp)) & 1ull;
        size_t koff = mrow ? (size_t)idx * (2 * D_HEAD) : 0;
        size_t voff = (mrow || allmasked) ? (size_t)idx * (2 * D_HEAD) : 0;
        kk[g] = *(const float4*)(dbb + koff + 4 * sub);
        vv[g] = *(const float4*)(dbb + voff + D_HEAD + 4 * sub);
    }

    // Dot products: 4-elem partial per lane, 4-step butterfly over 16 lanes
    float s8[8];
#pragma unroll
    for (int g = 0; g < 8; ++g) {
        float p = q4[0] * kk[g].x + q4[1] * kk[g].y + q4[2] * kk[g].z + q4[3] * kk[g].w;
        p += __shfl_xor(p, 1);
        p += __shfl_xor(p, 2);
        p += __shfl_xor(p, 4);
        p += __shfl_xor(p, 8);
        s8[g] = p;  // full dot of row 4g+grp (replicated in 16-lane group)
    }

    // Collect: lane j<32 takes s8[j>>2] from source lane (j&3)<<4
    float simlane = -INFINITY;
#pragma unroll
    for (int g = 0; g < 8; ++g) {
        float tv = __shfl(s8[g], (lane & 3) << 4);
        if ((lane >> 2) == g) simlane = tv;  // lanes>=32 never match: stay -inf
    }
    if (lane < K_NN)
        simlane = maskv ? simlane * scale : -3.402823466e38f;

    // Softmax across 64 lanes
    float m = simlane;
#pragma unroll
    for (int s = 32; s; s >>= 1) m = fmaxf(m, __shfl_xor(m, s));
    float w = __expf(simlane - m);
    float l = w;
#pragma unroll
    for (int s = 32; s; s >>= 1) l += __shfl_xor(l, s);
    float winv = w / l;

    // Weighted sum of V (float4 layout), then reduce across the 4 groups
    float4 o = {0.f, 0.f, 0.f, 0.f};
#pragma unroll
    for (int g = 0; g < 8; ++g) {
        float wg = __shfl(winv, 4 * g + grp);
        o.x = fmaf(wg, vv[g].x, o.x);
        o.y = fmaf(wg, vv[g].y, o.y);
        o.z = fmaf(wg, vv[g].z, o.z);
        o.w = fmaf(wg, vv[g].w, o.w);
    }
#pragma unroll
    for (int s = 16; s <= 32; s <<= 1) {
        o.x += __shfl_xor(o.x, s);
        o.y += __shfl_xor(o.y, s);
        o.z += __shfl_xor(o.z, s);
        o.w += __shfl_xor(o.w, s);
    }
    if (grp == 0) {
        ushort4 h, l4;
        split4(o, h, l4);
        size_t off = ((size_t)(bi * N_SEQ + i) * DIM + hi * D_HEAD + 4 * sub) >> 2;
        ((ushort4*)out_hi)[off] = h;
        ((ushort4*)out_lo)[off] = l4;
    }
}

// ---------------------------------------------------------------------------
extern "C" void kernel_launch(void* const* d_in, const int* in_sizes, int n_in,
                              void* d_out, int out_size, void* d_ws, size_t ws_size,
                              hipStream_t stream) {
    const float* x        = (const float*)d_in[0];
    const float* mem_db   = (const float*)d_in[1];
    const int*   knn_idx  = (const int*)d_in[2];
    const void*  mem_mask = d_in[3];
    const float* Wq       = (const float*)d_in[4];
    // d_in[5] = Wkv: dead code in the reference, unused.
    const float* Wout     = (const float*)d_in[6];
    const float* scale_p  = (const float*)d_in[7];
    float* out = (float*)d_out;

    const int Mrows = B_SZ * N_SEQ;  // 4096
    const int n_x   = Mrows * DIM;   // 2097152
    const int n_w   = DIM * DIM;     // 262144

    // Workspace: flag | qbuf fp32 (8MB) | x planes (8MB) | ao planes (8MB)
    //            | 4 weight planes (2MB)   -> ~26.3 MB total
    char* ws = (char*)d_ws;
    int* flag = (int*)ws;
    float* qbuf = (float*)(ws + 256);
    unsigned short* x_hi  = (unsigned short*)(qbuf + (size_t)n_x);
    unsigned short* x_lo  = x_hi + n_x;
    unsigned short* ao_hi = x_lo + n_x;
    unsigned short* ao_lo = ao_hi + n_x;
    unsigned short* wq_hi = ao_lo + n_x;
    unsigned short* wq_lo = wq_hi + n_w;
    unsigned short* wo_hi = wq_lo + n_w;
    unsigned short* wo_lo = wo_hi + n_w;

    prep_kernel<<<2561, 256, 0, stream>>>(
        (const float4*)x, (const float4*)Wq, (const float4*)Wout,
        (ushort4*)x_hi, (ushort4*)x_lo,
        (ushort4*)wq_hi, (ushort4*)wq_lo, (ushort4*)wo_hi, (ushort4*)wo_lo,
        (const unsigned char*)mem_mask, flag);

    dim3 ggrid(Mrows / 64, DIM / 64);  // (64, 8)
    gemm_mfma_planes<<<ggrid, 256, 0, stream>>>(x_hi, x_lo, wq_hi, wq_lo, qbuf,
                                                Mrows, DIM, DIM);

    const int n_waves = B_SZ * H_HEADS * N_SEQ;  // 32768
    attn_kernel<<<n_waves / 4, 256, 0, stream>>>(qbuf, mem_db, knn_idx, mem_mask,
                                                 scale_p, flag, ao_hi, ao_lo);

    gemm_mfma_planes<<<ggrid, 256, 0, stream>>>(ao_hi, ao_lo, wo_hi, wo_lo, out,
                                                Mrows, DIM, DIM);
}